// Round 4
// baseline (117.375 us; speedup 1.0000x reference)
//
#include <hip/hip_runtime.h>
#include <math.h>

#define DIM 32
#define NK  16
#define LOG2E 1.4426950408889634f

typedef __attribute__((ext_vector_type(8))) short bf16x8;
typedef __attribute__((ext_vector_type(4))) float f32x4;

#define MFMA16 __builtin_amdgcn_mfma_f32_16x16x32_bf16

// ws byte layout (precomputed by gmm_setup_kernel each launch):
#define WHI_OFF 0        // [NK][DIM][DIM] bf16 hi of W        (32768 B)
#define WLO_OFF 32768    // [NK][DIM][DIM] bf16 lo of W        (32768 B)
#define HH_OFF  65536    // [NK][DIM] bf16 hi of h*log2e       (1024 B)
#define HL_OFF  66560    // [NK][DIM] bf16 lo
#define GH_OFF  67584    // [NK][DIM] bf16 hi of (mu/s2)*log2e
#define GL_OFF  68608    // [NK][DIM] bf16 lo
#define CG_OFF  69632    // [NK] f32: log2(const_k) + sum(mu^2*h)*log2e

typedef __attribute__((address_space(1))) const unsigned int gu32;
typedef __attribute__((address_space(3))) unsigned int lu32;

// Truncation split: x ~= hi + lo keeping ~17 mantissa bits.
__device__ __forceinline__ void split2(float x, short* hi, short* lo) {
  unsigned u = __float_as_uint(x);
  *hi = (short)(u >> 16);
  float hf = __uint_as_float(u & 0xFFFF0000u);
  float l = x - hf;                       // exact residual
  *lo = (short)(__float_as_uint(l) >> 16);
}

__global__ __launch_bounds__(256) void gmm_setup_kernel(
    const float* __restrict__ mu, const float* __restrict__ logsigma,
    const float* __restrict__ W, char* __restrict__ ws)
{
  int i = blockIdx.x * 256 + threadIdx.x;
  short* whi = (short*)(ws + WHI_OFF);
  short* wlo = (short*)(ws + WLO_OFF);
  if (i < NK * DIM * DIM) split2(W[i], &whi[i], &wlo[i]);
  if (i < NK * DIM) {
    float s2 = __expf(2.0f * logsigma[i]);
    float h = (-0.5f / s2) * LOG2E;       // exp2 later (log2e folded)
    float g = (mu[i] / s2) * LOG2E;
    short a, b;
    split2(h, &a, &b);
    ((short*)(ws + HH_OFF))[i] = a; ((short*)(ws + HL_OFF))[i] = b;
    split2(g, &a, &b);
    ((short*)(ws + GH_OFF))[i] = a; ((short*)(ws + GL_OFF))[i] = b;
  }
  if (i < NK) {
    float acc = 0.0f;
    for (int d = 0; d < DIM; ++d) {
      float s2 = __expf(2.0f * logsigma[i * DIM + d]);
      float m  = mu[i * DIM + d];
      acc += m * m * (-0.5f / s2) * LOG2E - 0.5f * log2f(6.283185307179586f * s2);
    }
    ((float*)(ws + CG_OFF))[i] = acc;
  }
}

// 512-thread block = 8 waves; each wave owns M=32 samples (2 tiles of 16).
// mfma_f32_16x16x32_bf16: A/B frag row/col = lane%16, k = (lane/16)*8 + j;
// D: col = lane&15, row = (lane>>4)*4 + reg      [m89-verified]
// Full W split (whi+wlo, 64 KB) staged to LDS once/block -> k-loop reads are
// ds_read_b128 at base+imm offsets (zero addr VALU). Gate weights stay in
// registers; k-loop broadcasts w(sample,k) from lane (lane&48)|k via __shfl.
// LDS = 64 KB static -> 2 blocks/CU, 16 waves/CU; grid 1024 = 4 blocks/CU
// in 2 clean residency batches.
__global__ __launch_bounds__(512, 4) void gmm_moe_kernel(
    const float* __restrict__ x,
    const float* __restrict__ bias,
    const char* __restrict__ ws,
    float* __restrict__ out)
{
  __shared__ char lds_w[65536];           // linear copy of whi||wlo
  const int tid  = threadIdx.x;
  const int wid  = tid >> 6;
  const int lane = tid & 63;
  const int g = lane >> 4;                // k-chunk / row-group
  const int c = lane & 15;                // A-row (sample) & B-col index
  const int sbase = (blockIdx.x * 8 + wid) * 32;

  // ---- stage whi+wlo (64 KB) into LDS: 8 rounds x (8 waves x 1 KB) ----
  #pragma unroll
  for (int r = 0; r < 8; ++r) {
    const int off = r * 8192 + wid * 1024;
    __builtin_amdgcn_global_load_lds(
        (gu32*)(ws + off + lane * 16), (lu32*)(lds_w + off), 16, 0, 0);
  }

  // ---- x loads (2 tiles x 32 B per lane) ----
  float4 xa[2][2];
  #pragma unroll
  for (int t = 0; t < 2; ++t) {
    const float4* xp =
        (const float4*)(x + (size_t)(sbase + t * 16 + c) * DIM + g * 8);
    xa[t][0] = xp[0];
    xa[t][1] = xp[1];
  }

  // ---- gate tables (small, L2-hot) ----
  const bf16x8 fhh = ((const bf16x8*)(ws + HH_OFF))[c * 4 + g];
  const bf16x8 fhl = ((const bf16x8*)(ws + HL_OFF))[c * 4 + g];
  const bf16x8 fgh = ((const bf16x8*)(ws + GH_OFF))[c * 4 + g];
  const bf16x8 fgl = ((const bf16x8*)(ws + GL_OFF))[c * 4 + g];
  const float  cgv = ((const float*)(ws + CG_OFF))[c];

  // ---- gate: exponent via split-bf16 MFMA, exp2, shfl-sum, normalize ----
  // overlaps the global_load_lds staging latency (no LDS dependence here)
  bf16x8 xh[2], xl[2];
  f32x4 wv[2];                            // w(sample g*4+r, expert c), per tile
  #pragma unroll
  for (int t = 0; t < 2; ++t) {
    float xv[8] = {xa[t][0].x, xa[t][0].y, xa[t][0].z, xa[t][0].w,
                   xa[t][1].x, xa[t][1].y, xa[t][1].z, xa[t][1].w};
    bf16x8 x2h, x2l;
    #pragma unroll
    for (int j = 0; j < 8; ++j) {
      short h_, l_;
      split2(xv[j], &h_, &l_);
      xh[t][j] = h_; xl[t][j] = l_;
      float q = xv[j] * xv[j];
      split2(q, &h_, &l_);
      x2h[j] = h_; x2l[j] = l_;
    }
    f32x4 e = {cgv, cgv, cgv, cgv};
    e = MFMA16(x2h,   fhh, e, 0, 0, 0);
    e = MFMA16(x2l,   fhh, e, 0, 0, 0);
    e = MFMA16(x2h,   fhl, e, 0, 0, 0);
    e = MFMA16(xh[t], fgh, e, 0, 0, 0);
    e = MFMA16(xl[t], fgh, e, 0, 0, 0);
    e = MFMA16(xh[t], fgl, e, 0, 0, 0);
    // e[r] = log2(p) for sample (g*4+r), expert c
    #pragma unroll
    for (int r = 0; r < 4; ++r) {
      float p = __builtin_amdgcn_exp2f(e[r]);
      float s = p;
      s += __shfl_xor(s, 1, 64);
      s += __shfl_xor(s, 2, 64);
      s += __shfl_xor(s, 4, 64);
      s += __shfl_xor(s, 8, 64);          // sum over the 16 experts
      wv[t][r] = p * __builtin_amdgcn_rcpf(s);
    }
  }

  // barrier: vmcnt(0) drain guarantees W staging is complete for all waves
  __syncthreads();

  // ---- expert loop: C = relu(x W_k^T + b_k), out += w_k * C ----
  f32x4 o0[2], o1[2];
  #pragma unroll
  for (int t = 0; t < 2; ++t) { o0[t] = (f32x4){0,0,0,0}; o1[t] = (f32x4){0,0,0,0}; }

  const int wbase = c * 64 + g * 16;      // lane's chunk within a 2 KB W[k] row
  #pragma unroll
  for (int k = 0; k < NK; ++k) {
    const bf16x8 w0h = *(const bf16x8*)(lds_w + k * 2048 + wbase);
    const bf16x8 w1h = *(const bf16x8*)(lds_w + k * 2048 + 1024 + wbase);
    const bf16x8 w0l = *(const bf16x8*)(lds_w + 32768 + k * 2048 + wbase);
    const bf16x8 w1l = *(const bf16x8*)(lds_w + 32768 + k * 2048 + 1024 + wbase);
    const float b0 = bias[k * DIM + c];
    const float b1 = bias[k * DIM + 16 + c];
    #pragma unroll
    for (int t = 0; t < 2; ++t) {
      f32x4 s0 = {b0, b0, b0, b0}, s1 = {b1, b1, b1, b1};
      s0 = MFMA16(xh[t], w0h, s0, 0, 0, 0);
      s0 = MFMA16(xl[t], w0h, s0, 0, 0, 0);
      s0 = MFMA16(xh[t], w0l, s0, 0, 0, 0);
      s1 = MFMA16(xh[t], w1h, s1, 0, 0, 0);
      s1 = MFMA16(xl[t], w1h, s1, 0, 0, 0);
      s1 = MFMA16(xh[t], w1l, s1, 0, 0, 0);
      // broadcast gate weight w(sample g*4+r, k) from lane (g*16 + k)
      f32x4 wb;
      #pragma unroll
      for (int r = 0; r < 4; ++r)
        wb[r] = __shfl(wv[t][r], (lane & 48) | k, 64);
      const f32x4 z = {0.0f, 0.0f, 0.0f, 0.0f};
      o0[t] = __builtin_elementwise_fma(wb, __builtin_elementwise_max(s0, z), o0[t]);
      o1[t] = __builtin_elementwise_fma(wb, __builtin_elementwise_max(s1, z), o1[t]);
    }
  }

  // ---- store: lane (g,c) holds rows g*4+r of each tile, cols c and c+16 ----
  #pragma unroll
  for (int t = 0; t < 2; ++t) {
    #pragma unroll
    for (int r = 0; r < 4; ++r) {
      size_t row = (size_t)(sbase + t * 16 + g * 4 + r);
      out[row * DIM + c]      = o0[t][r];
      out[row * DIM + 16 + c] = o1[t][r];
    }
  }
}

extern "C" void kernel_launch(void* const* d_in, const int* in_sizes, int n_in,
                              void* d_out, int out_size, void* d_ws, size_t ws_size,
                              hipStream_t stream) {
  const float* x  = (const float*)d_in[0];   // [B, DIM]
  const float* mu = (const float*)d_in[1];   // [NK, DIM]
  const float* ls = (const float*)d_in[2];   // [NK, DIM]
  const float* W  = (const float*)d_in[3];   // [NK, DIM, DIM]
  const float* bv = (const float*)d_in[4];   // [NK, DIM]
  float* out = (float*)d_out;
  const int B = in_sizes[0] / DIM;

  gmm_setup_kernel<<<(NK * DIM * DIM + 255) / 256, 256, 0, stream>>>(
      mu, ls, W, (char*)d_ws);
  // 512 threads = 8 waves x 32 samples = 256 samples/block
  gmm_moe_kernel<<<B / 256, 512, 0, stream>>>(x, bv, (const char*)d_ws, out);
}

// Round 5
// 116.004 us; speedup vs baseline: 1.0118x; 1.0118x over previous
//
#include <hip/hip_runtime.h>
#include <math.h>

#define DIM 32
#define NK  16
#define LOG2E 1.4426950408889634f

typedef __attribute__((ext_vector_type(8))) short bf16x8;
typedef __attribute__((ext_vector_type(4))) float f32x4;

#define MFMA16 __builtin_amdgcn_mfma_f32_16x16x32_bf16

// ws byte layout (precomputed by gmm_setup_kernel each launch):
// W frags stored in LANE-LINEAR order: frag f = [k][o16][lane], 16B each.
//   content: lane=(g,c) -> W[k][o16*16+c][g*8 .. g*8+7] (bf16 hi / lo)
#define WHIF_OFF 0       // [16][2][64] 16B frags = 32768 B  (staged to LDS)
#define WLOF_OFF 32768   // [16][2][64] 16B frags = 32768 B  (stays global/L1)
#define HH_OFF  65536    // [NK][DIM] bf16 hi of h*log2e
#define HL_OFF  66560    // [NK][DIM] bf16 lo
#define GH_OFF  67584    // [NK][DIM] bf16 hi of (mu/s2)*log2e
#define GL_OFF  68608    // [NK][DIM] bf16 lo
#define CG_OFF  69632    // [NK] f32: log2(const_k) + sum(mu^2*h)*log2e

typedef __attribute__((address_space(1))) const unsigned int gu32;
typedef __attribute__((address_space(3))) unsigned int lu32;

// LDS geometry: lds_w frags 32768 B, then per-wave gate-weight transpose
// lds_p: [16 k][stride 144 B] (36 words: write banks 4(c+g)%32 per 8-lane
// chunk = conflict-free; 144%16==0 keeps b128 alignment). 2304 B/wave.
#define LDSP_BASE 32768
#define LDSP_WAVE 2304
#define LDS_TOTAL (32768 + 4 * LDSP_WAVE)   // 41984 -> 3 blocks/CU

// Truncation split: x ~= hi + lo keeping ~17 mantissa bits.
__device__ __forceinline__ void split2(float x, short* hi, short* lo) {
  unsigned u = __float_as_uint(x);
  *hi = (short)(u >> 16);
  float hf = __uint_as_float(u & 0xFFFF0000u);
  float l = x - hf;                       // exact residual
  *lo = (short)(__float_as_uint(l) >> 16);
}

__global__ __launch_bounds__(256) void gmm_setup_kernel(
    const float* __restrict__ mu, const float* __restrict__ logsigma,
    const float* __restrict__ W, char* __restrict__ ws)
{
  int i = blockIdx.x * 256 + threadIdx.x;
  // ---- W frags, lane-linear: f = k*128 + o16*64 + lane ----
  if (i < NK * 2 * 64) {
    const int k = i >> 7, o16 = (i >> 6) & 1, lane = i & 63;
    const int c = lane & 15, g = lane >> 4;
    const int o = o16 * 16 + c;
    bf16x8 hi, lo;
    #pragma unroll
    for (int j = 0; j < 8; ++j) {
      short h_, l_;
      split2(W[(k * DIM + o) * DIM + g * 8 + j], &h_, &l_);
      hi[j] = h_; lo[j] = l_;
    }
    ((bf16x8*)(ws + WHIF_OFF))[i] = hi;
    ((bf16x8*)(ws + WLOF_OFF))[i] = lo;
  }
  // ---- gate tables ----
  if (i < NK * DIM) {
    float s2 = __expf(2.0f * logsigma[i]);
    float h = (-0.5f / s2) * LOG2E;       // exp2 later (log2e folded)
    float g = (mu[i] / s2) * LOG2E;
    short a, b;
    split2(h, &a, &b);
    ((short*)(ws + HH_OFF))[i] = a; ((short*)(ws + HL_OFF))[i] = b;
    split2(g, &a, &b);
    ((short*)(ws + GH_OFF))[i] = a; ((short*)(ws + GL_OFF))[i] = b;
  }
  if (i < NK) {
    float acc = 0.0f;
    for (int d = 0; d < DIM; ++d) {
      float s2 = __expf(2.0f * logsigma[i * DIM + d]);
      float m  = mu[i * DIM + d];
      acc += m * m * (-0.5f / s2) * LOG2E - 0.5f * log2f(6.283185307179586f * s2);
    }
    ((float*)(ws + CG_OFF))[i] = acc;
  }
}

// 256-thread block = 4 waves x M=32 samples = 128 samples/block.
// mfma_f32_16x16x32_bf16: A/B frag row/col = lane%16, k = (lane/16)*8 + j;
// D: col = lane&15, row = (lane>>4)*4 + reg      [m89-verified]
// whi frags staged to LDS (conflict-free lane-linear b128 reads, imm offsets);
// wlo frags read from global (coalesced 1KB loads, 32KB L1-resident);
// gate weights transposed once through padded lds_p (broadcast b128 reads).
__global__ __launch_bounds__(256, 3) void gmm_moe_kernel(
    const float* __restrict__ x,
    const float* __restrict__ bias,
    const char* __restrict__ ws,
    float* __restrict__ out)
{
  __shared__ char lds[LDS_TOTAL];
  const int tid  = threadIdx.x;
  const int wid  = tid >> 6;
  const int lane = tid & 63;
  const int g = lane >> 4;                // k-chunk / row-group
  const int c = lane & 15;                // A-row (sample) & B-col index
  const int sbase = (blockIdx.x * 4 + wid) * 32;

  // ---- stage whi frags (32KB) to LDS: 8 rounds x (4 waves x 1KB) ----
  #pragma unroll
  for (int r = 0; r < 8; ++r) {
    const int off = r * 4096 + wid * 1024;
    __builtin_amdgcn_global_load_lds(
        (gu32*)(ws + WHIF_OFF + off + lane * 16), (lu32*)(lds + off), 16, 0, 0);
  }

  // ---- x loads (2 tiles x 32 B per lane) ----
  float4 xa[2][2];
  #pragma unroll
  for (int t = 0; t < 2; ++t) {
    const float4* xp =
        (const float4*)(x + (size_t)(sbase + t * 16 + c) * DIM + g * 8);
    xa[t][0] = xp[0];
    xa[t][1] = xp[1];
  }

  // ---- gate tables (small, L2-hot) ----
  const bf16x8 fhh = ((const bf16x8*)(ws + HH_OFF))[c * 4 + g];
  const bf16x8 fhl = ((const bf16x8*)(ws + HL_OFF))[c * 4 + g];
  const bf16x8 fgh = ((const bf16x8*)(ws + GH_OFF))[c * 4 + g];
  const bf16x8 fgl = ((const bf16x8*)(ws + GL_OFF))[c * 4 + g];
  const float  cgv = ((const float*)(ws + CG_OFF))[c];

  // ---- gate: exponent via split-bf16 MFMA, exp2, shfl-sum, normalize ----
  // (overlaps the global_load_lds staging; no LDS dependence here)
  bf16x8 xh[2], xl[2];
  f32x4 wv[2];                            // w(sample g*4+r, expert c), per tile
  #pragma unroll
  for (int t = 0; t < 2; ++t) {
    float xv[8] = {xa[t][0].x, xa[t][0].y, xa[t][0].z, xa[t][0].w,
                   xa[t][1].x, xa[t][1].y, xa[t][1].z, xa[t][1].w};
    bf16x8 x2h, x2l;
    #pragma unroll
    for (int j = 0; j < 8; ++j) {
      short h_, l_;
      split2(xv[j], &h_, &l_);
      xh[t][j] = h_; xl[t][j] = l_;
      float q = xv[j] * xv[j];
      split2(q, &h_, &l_);
      x2h[j] = h_; x2l[j] = l_;
    }
    f32x4 e = {cgv, cgv, cgv, cgv};
    e = MFMA16(x2h,   fhh, e, 0, 0, 0);
    e = MFMA16(x2l,   fhh, e, 0, 0, 0);
    e = MFMA16(x2h,   fhl, e, 0, 0, 0);
    e = MFMA16(xh[t], fgh, e, 0, 0, 0);
    e = MFMA16(xl[t], fgh, e, 0, 0, 0);
    e = MFMA16(xh[t], fgl, e, 0, 0, 0);
    // e[r] = log2(p) for sample (g*4+r), expert c
    #pragma unroll
    for (int r = 0; r < 4; ++r) {
      float p = __builtin_amdgcn_exp2f(e[r]);
      float s = p;
      s += __shfl_xor(s, 1, 64);
      s += __shfl_xor(s, 2, 64);
      s += __shfl_xor(s, 4, 64);
      s += __shfl_xor(s, 8, 64);          // sum over the 16 experts
      wv[t][r] = p * __builtin_amdgcn_rcpf(s);
    }
  }

  // ---- transpose gate weights once: lane (g,c) writes w(samples, expert c)
  // write addr: c*144 + t*64 + g*16 -> per-8-lane-chunk banks 4(c+g)%32:
  // all 32 banks covered, conflict-free.
  {
    char* pw = lds + LDSP_BASE + wid * LDSP_WAVE + c * 144 + g * 16;
    *(f32x4*)(pw)      = wv[0];
    *(f32x4*)(pw + 64) = wv[1];
  }

  // barrier: drains vmcnt(0) (staging) + lgkm (lds_p writes) for all waves
  __syncthreads();

  // ---- expert loop: C = relu(x W_k^T + b_k), out += w_k * C ----
  const bf16x8* wlof = (const bf16x8*)(ws + WLOF_OFF);
  const char*   ldsp = lds + LDSP_BASE + wid * LDSP_WAVE + g * 16;
  f32x4 o0[2], o1[2];
  #pragma unroll
  for (int t = 0; t < 2; ++t) { o0[t] = (f32x4){0,0,0,0}; o1[t] = (f32x4){0,0,0,0}; }

  #pragma unroll
  for (int k = 0; k < NK; ++k) {
    // whi frags from LDS: lane-linear, conflict-free, imm offsets
    const bf16x8 w0h = *(const bf16x8*)(lds + (k * 2 + 0) * 1024 + lane * 16);
    const bf16x8 w1h = *(const bf16x8*)(lds + (k * 2 + 1) * 1024 + lane * 16);
    // wlo frags from global: coalesced 1KB/instr, 32KB hot set ~ L1
    const bf16x8 w0l = wlof[(k * 2 + 0) * 64 + lane];
    const bf16x8 w1l = wlof[(k * 2 + 1) * 64 + lane];
    const float b0 = bias[k * DIM + c];
    const float b1 = bias[k * DIM + 16 + c];
    #pragma unroll
    for (int t = 0; t < 2; ++t) {
      f32x4 s0 = {b0, b0, b0, b0}, s1 = {b1, b1, b1, b1};
      s0 = MFMA16(xh[t], w0h, s0, 0, 0, 0);
      s0 = MFMA16(xl[t], w0h, s0, 0, 0, 0);
      s0 = MFMA16(xh[t], w0l, s0, 0, 0, 0);
      s1 = MFMA16(xh[t], w1h, s1, 0, 0, 0);
      s1 = MFMA16(xl[t], w1h, s1, 0, 0, 0);
      s1 = MFMA16(xh[t], w1l, s1, 0, 0, 0);
      // gate weights: broadcast b128 read (lanes differ only in g)
      const f32x4 wb = *(const f32x4*)(ldsp + k * 144 + t * 64);
      const f32x4 z = {0.0f, 0.0f, 0.0f, 0.0f};
      o0[t] = __builtin_elementwise_fma(wb, __builtin_elementwise_max(s0, z), o0[t]);
      o1[t] = __builtin_elementwise_fma(wb, __builtin_elementwise_max(s1, z), o1[t]);
    }
  }

  // ---- store: lane (g,c) holds rows g*4+r of each tile, cols c and c+16 ----
  #pragma unroll
  for (int t = 0; t < 2; ++t) {
    #pragma unroll
    for (int r = 0; r < 4; ++r) {
      size_t row = (size_t)(sbase + t * 16 + g * 4 + r);
      out[row * DIM + c]      = o0[t][r];
      out[row * DIM + 16 + c] = o1[t][r];
    }
  }
}

extern "C" void kernel_launch(void* const* d_in, const int* in_sizes, int n_in,
                              void* d_out, int out_size, void* d_ws, size_t ws_size,
                              hipStream_t stream) {
  const float* x  = (const float*)d_in[0];   // [B, DIM]
  const float* mu = (const float*)d_in[1];   // [NK, DIM]
  const float* ls = (const float*)d_in[2];   // [NK, DIM]
  const float* W  = (const float*)d_in[3];   // [NK, DIM, DIM]
  const float* bv = (const float*)d_in[4];   // [NK, DIM]
  float* out = (float*)d_out;
  const int B = in_sizes[0] / DIM;

  gmm_setup_kernel<<<8, 256, 0, stream>>>(mu, ls, W, (char*)d_ws);
  // 256 threads = 4 waves x 32 samples = 128 samples/block
  gmm_moe_kernel<<<B / 128, 256, 0, stream>>>(x, bv, (const char*)d_ws, out);
}